// Round 5
// baseline (4936.926 us; speedup 1.0000x reference)
//
#include <hip/hip_runtime.h>
#include <cmath>
#include <climits>

#define N_ 2048
#define T_ 4096
#define MAXSP 256
#define CHUNK 256
#define NCHUNK (T_ / CHUNK)   // 16
#define NBODY (CHUNK / 2)     // 128 two-step bodies per chunk

// ---------------- workspace layout (d_ws) ----------------
#define WS_EIDX_OFF   0
#define WS_CNT_OFF    (T_ * 4)
#define WS_SNAP_OFF   (T_ * 4 + NCHUNK * 4)

typedef float f2 __attribute__((ext_vector_type(2)));

__device__ __forceinline__ int imin(int a, int b) { return a < b ? a : b; }

// Raw workgroup barrier with LDS visibility only (no vmcnt drain):
// global prefetches (ic, u_re, w-row) stay in flight across it.
__device__ __forceinline__ void lds_barrier() {
    asm volatile("s_waitcnt lgkmcnt(0)\n\ts_barrier" ::: "memory");
}

// Fill tevents/yevents with +inf, event_types with 0.
__global__ void snn_init_tail(float* __restrict__ out) {
    const size_t base    = (size_t)T_ * N_ * 3;
    const size_t inf_cnt = (size_t)MAXSP + (size_t)MAXSP * N_ * 3;
    const size_t tot     = inf_cnt + (size_t)MAXSP * N_;
    size_t idx = (size_t)blockIdx.x * blockDim.x + threadIdx.x;
    if (idx < tot) {
        out[base + idx] = (idx < inf_cnt) ? __builtin_inff() : 0.0f;
    }
}

// ---------------- Kernel A: sequential scan (1 WG, 2 steps / barrier) ----
// R1's proven geometry (1024 thr x f2, 16 waves) and exact per-step op
// order, but each loop body advances TWO timesteps with ONE barrier:
//   mask_a -> atomicMin[2p]  (from state after step a-1)
//   Euler-a, v_a, s_a        (eidx-free: reset/resample depend on mask only)
//   mask_b -> atomicMin[2p+1] (from v_a, s_a)
//   lds_barrier; ds_read_b64 -> (eidx_a, eidx_b)
//   i_a (+w row), Euler-b, v_b, s_b, i_b (+w row)
// Valid because i enters v with a one-step lag: mask_{k+1} needs only
// (v_k, s_k), never i_k.  All arithmetic is bit-identical to R1.
extern "C" __global__ void __launch_bounds__(1024)
snn_scan(const float* __restrict__ w,   const float* __restrict__ mu,
         const float* __restrict__ v0,  const float* __restrict__ i0,
         const float* __restrict__ ic,  const float* __restrict__ u_init,
         const float* __restrict__ u_re, float* __restrict__ out,
         int* __restrict__ ws_eidx, int* __restrict__ ws_cnt,
         float* __restrict__ ws_snap)
{
#pragma clang fp contract(off)
    const int tid = threadIdx.x;
    const int n0  = tid * 2;             // two adjacent neurons -> f2 ops
    const int wv  = tid >> 6, lane = tid & 63;
    const float dt = 1.0f / 4096.0f;     // exact: 2^-12
    const float mu1 = mu[0], mu2 = mu[1];

    float* tev = out + (size_t)T_ * N_ * 3;
    float* nsp = tev + MAXSP + (size_t)MAXSP * N_ * 3 + (size_t)MAXSP * N_;

    // state after step (body_start - 1): vP, sP, iP (iP includes any w row)
    f2 vP, sP, iP;
    vP = *(const f2*)(v0 + n0);
    iP = *(const f2*)(i0 + n0);
    { f2 a_ = *(const f2*)(u_init + n0);
      sP.x = logf(a_.x) - 0.01f; sP.y = logf(a_.y) - 0.01f; }  // one-time precise

    // 8 slots = 4 pairs.  Body J uses pair (J&3) = slots {2(J&3), 2(J&3)+1}.
    // tid0 resets pair (J+2)&3 right after body J's barrier:
    //   last reads of that pair: body J-2 (post-barrier)  -> barriers J-1, J between
    //   next atomics to it:      body J+2 (pre-barrier)   -> barrier J+1 between
    __shared__ __align__(16) int red[8];
    if (tid == 0) {
        red[0] = INT_MAX; red[1] = INT_MAX; red[2] = INT_MAX; red[3] = INT_MAX;
        red[4] = INT_MAX; red[5] = INT_MAX; red[6] = INT_MAX; red[7] = INT_MAX;
    }

    // prefetch: cur = rows (a, a+1) in ic0/ic1/u0/u1,
    //           nxt = rows (a+2, a+3) in ic2/ic3/u2/u3.
    // At body end: shift nxt->cur, load rows (a+4, a+5) into nxt
    // (consumed at body J+2 -> ~1.3 bodies of slack).
    const float* icp = ic + n0;
    const float* up  = u_re + n0;
    f2 ic0 = *(const f2*)(icp);
    f2 ic1 = *(const f2*)(icp + N_);
    f2 ic2 = *(const f2*)(icp + 2 * N_);
    f2 ic3 = *(const f2*)(icp + 3 * N_);
    f2 u0  = *(const f2*)(up);
    f2 u1  = *(const f2*)(up + N_);
    f2 u2  = *(const f2*)(up + 2 * N_);
    f2 u3  = *(const f2*)(up + 3 * N_);
    icp += 4 * N_; up += 4 * N_;

    lds_barrier();   // red[] init visible before first atomics

    int cnt = 0;
    for (int c = 0; c < NCHUNK; ++c) {
        // chunk snapshot: state after step c*256 - 1 (= chunk-start state)
        {
            float* spn = ws_snap + (size_t)c * 3 * N_;
            *(f2*)(spn + n0)          = vP;
            *(f2*)(spn + N_ + n0)     = iP;
            *(f2*)(spn + 2 * N_ + n0) = sP;
            if (tid == 0) ws_cnt[c] = cnt;
        }

        for (int j = 0; j < NBODY; ++j) {
            const int a  = (c << 8) + (j << 1);        // first step of body
            const int bj = (c << 7) + j;               // body index
            const int p  = (bj & 3) << 1;              // slot-pair base

            // ---- [a1] softplus + mask_a (from vP, sP) -------------------
            // Fast path: for v >= 16, fmax(v,0)+__logf(1+__expf(-|v|))
            // rounds to EXACTLY v in fp32 -> bit-identical; transcendental
            // path only if any lane in the wave has v < 16.
            f2 spA;
            bool slowA = (fminf(vP.x, vP.y) < 16.0f);
            if (__ballot(slowA)) {
                spA.x = fmaxf(vP.x, 0.0f) + __logf(1.0f + __expf(-fabsf(vP.x)));
                spA.y = fmaxf(vP.y, 0.0f) + __logf(1.0f + __expf(-fabsf(vP.y)));
            } else {
                spA = vP;
            }
            f2 s1a = sP + dt * spA;
            bool ma0 = (s1a.x >= 0.0f), ma1 = (s1a.y >= 0.0f);
            unsigned long long ba0 = __ballot(ma0);
            unsigned long long ba1 = __ballot(ma1);
            bool anyA = ((ba0 | ba1) != 0ull);
            if (anyA) {
                int c0 = ba0 ? (((int)__ffsll((long long)ba0) - 1) << 1)       : INT_MAX;
                int c1 = ba1 ? ((((int)__ffsll((long long)ba1) - 1) << 1) | 1) : INT_MAX;
                int cand = (wv << 7) + imin(c0, c1);
                if (lane == 0) atomicMin(&red[p], cand);
            }

            // ---- [a2] Euler-a + eidx-free transitions -------------------
            f2 v1a = vP + dt * (mu1 * ((iP + ic0) - vP));
            f2 i1a = iP + dt * ((-mu2) * iP);
            f2 va, sa;
            va.x = ma0 ? (v1a.x - 1.0f) : v1a.x;
            va.y = ma1 ? (v1a.y - 1.0f) : v1a.y;
            if (anyA) {
                sa.x = ma0 ? (__logf(u0.x) - 0.01f) : s1a.x;
                sa.y = ma1 ? (__logf(u0.y) - 0.01f) : s1a.y;
            } else {
                sa = s1a;
            }

            // ---- [b1] softplus + mask_b (from va, sa) -------------------
            f2 spB;
            bool slowB = (fminf(va.x, va.y) < 16.0f);
            if (__ballot(slowB)) {
                spB.x = fmaxf(va.x, 0.0f) + __logf(1.0f + __expf(-fabsf(va.x)));
                spB.y = fmaxf(va.y, 0.0f) + __logf(1.0f + __expf(-fabsf(va.y)));
            } else {
                spB = va;
            }
            f2 s1b = sa + dt * spB;
            bool mb0 = (s1b.x >= 0.0f), mb1 = (s1b.y >= 0.0f);
            unsigned long long bb0 = __ballot(mb0);
            unsigned long long bb1 = __ballot(mb1);
            bool anyB = ((bb0 | bb1) != 0ull);
            if (anyB) {
                int c0 = bb0 ? (((int)__ffsll((long long)bb0) - 1) << 1)       : INT_MAX;
                int c1 = bb1 ? ((((int)__ffsll((long long)bb1) - 1) << 1) | 1) : INT_MAX;
                int cand = (wv << 7) + imin(c0, c1);
                if (lane == 0) atomicMin(&red[p + 1], cand);
            }

            // ---- ONE barrier for both steps; b64 read returns both ------
            lds_barrier();
            int2 rr = *(const int2*)(&red[p]);
            int eA = __builtin_amdgcn_readfirstlane(rr.x);
            int eB = __builtin_amdgcn_readfirstlane(rr.y);
            if (tid == 0) {                       // reset pair of body J+2
                const int q = (p + 4) & 7;
                red[q] = INT_MAX; red[q + 1] = INT_MAX;
            }

            // ---- finalize i_a (+ bookkeeping a) -------------------------
            f2 iA = i1a;
            if (eA != INT_MAX) {
                f2 wA = *(const f2*)(w + (size_t)eA * N_ + n0);
                iA += wA;
                if (tid == 0) {
                    ws_eidx[a] = eA;
                    if (cnt < MAXSP) tev[cnt] = (float)(a + 1) * dt;
                }
                if (cnt < MAXSP) cnt++;
            } else if (tid == 0) {
                ws_eidx[a] = -1;
            }

            // ---- Euler-b + transitions ----------------------------------
            f2 v1b = va + dt * (mu1 * ((iA + ic1) - va));
            f2 i1b = iA + dt * ((-mu2) * iA);
            vP.x = mb0 ? (v1b.x - 1.0f) : v1b.x;
            vP.y = mb1 ? (v1b.y - 1.0f) : v1b.y;
            if (anyB) {
                sP.x = mb0 ? (__logf(u1.x) - 0.01f) : s1b.x;
                sP.y = mb1 ? (__logf(u1.y) - 0.01f) : s1b.y;
            } else {
                sP = s1b;
            }

            f2 iB = i1b;
            if (eB != INT_MAX) {
                f2 wB = *(const f2*)(w + (size_t)eB * N_ + n0);
                iB += wB;
                if (tid == 0) {
                    ws_eidx[a + 1] = eB;
                    if (cnt < MAXSP) tev[cnt] = (float)(a + 2) * dt;
                }
                if (cnt < MAXSP) cnt++;
            } else if (tid == 0) {
                ws_eidx[a + 1] = -1;
            }
            iP = iB;

            // ---- rotate prefetch; issue rows a+4, a+5 (body J+2) --------
            ic0 = ic2; ic1 = ic3; u0 = u2; u1 = u3;
            if (a + 6 <= T_) {
                ic2 = *(const f2*)(icp);
                ic3 = *(const f2*)(icp + N_);
                u2  = *(const f2*)(up);
                u3  = *(const f2*)(up + N_);
                icp += 2 * N_; up += 2 * N_;
            }
        }
    }

    if (tid == 0) nsp[0] = (float)cnt;
}

// ---------------- Kernel B: parallel replay ----------------
extern "C" __global__ void __launch_bounds__(256)
snn_replay(const float* __restrict__ w,   const float* __restrict__ mu,
           const float* __restrict__ ic,  const float* __restrict__ u_re,
           float* __restrict__ out,
           const int* __restrict__ ws_eidx, const int* __restrict__ ws_cnt,
           const float* __restrict__ ws_snap)
{
#pragma clang fp contract(off)
    const int c = blockIdx.x >> 3;                       // chunk
    const int n = ((blockIdx.x & 7) << 8) + threadIdx.x; // neuron
    const float dt = 1.0f / 4096.0f;
    const float mu1 = mu[0], mu2 = mu[1];

    float* ys  = out;
    float* yev = out + (size_t)T_ * N_ * 3 + MAXSP;
    float* et  = yev + (size_t)MAXSP * N_ * 3;

    const float* sp = ws_snap + (size_t)c * 3 * N_;
    float v  = sp[n];
    float ii = sp[N_ + n];
    float ss = sp[2 * N_ + n];
    int cnt = ws_cnt[c];

    const int t0 = c << 8;
    const float* icp = ic + (size_t)t0 * N_ + n;
    const float* up  = u_re + (size_t)t0 * N_ + n;
    float* yr = ys + ((size_t)t0 * N_ + n) * 3;

    for (int k = 0; k < CHUNK; ++k) {
        const int t = t0 + k;
        const int e = ws_eidx[t];          // uniform scalar load
        const float icv = icp[0];

        float v1 = v + dt * (mu1 * ((ii + icv) - v));
        float i1 = ii + dt * ((-mu2) * ii);
        // same bit-exact fast/slow softplus as the scan
        float spv;
        if (__ballot(v < 16.0f)) {
            spv = fmaxf(v, 0.0f) + __logf(1.0f + __expf(-fabsf(v)));
        } else {
            spv = v;
        }
        float s1 = ss + dt * spv;
        bool m = (s1 >= 0.0f);

        if (e >= 0) {                      // event step (uniform branch)
            float wv_ = w[(size_t)e * N_ + n];
            float uu  = up[0];
            if (cnt < MAXSP) {             // record pre-transition state
                float* ye = yev + ((size_t)cnt * N_ + n) * 3;
                ye[0] = v1; ye[1] = i1; ye[2] = s1;
                et[(size_t)cnt * N_ + n] = m ? 1.0f : 0.0f;
                cnt++;
            }
            v  = m ? (v1 - 1.0f) : v1;
            ii = i1 + wv_;
            ss = m ? (__logf(uu) - 0.01f) : s1;
        } else {
            v = v1; ii = i1; ss = s1;
        }

        yr[0] = v; yr[1] = ii; yr[2] = ss;

        icp += N_; up += N_; yr += (size_t)3 * N_;
    }
}

extern "C" void kernel_launch(void* const* d_in, const int* in_sizes, int n_in,
                              void* d_out, int out_size, void* d_ws, size_t ws_size,
                              hipStream_t stream) {
    const float* w      = (const float*)d_in[0];
    const float* mu     = (const float*)d_in[1];
    const float* v0     = (const float*)d_in[2];
    const float* i0     = (const float*)d_in[3];
    const float* ic     = (const float*)d_in[4];
    const float* u_init = (const float*)d_in[5];
    const float* u_re   = (const float*)d_in[6];
    float* out = (float*)d_out;

    char* ws = (char*)d_ws;
    int*   ws_eidx = (int*)(ws + WS_EIDX_OFF);
    int*   ws_cnt  = (int*)(ws + WS_CNT_OFF);
    float* ws_snap = (float*)(ws + WS_SNAP_OFF);

    const size_t tail = (size_t)MAXSP + (size_t)MAXSP * N_ * 3 + (size_t)MAXSP * N_;
    int blocks = (int)((tail + 255) / 256);
    snn_init_tail<<<blocks, 256, 0, stream>>>(out);

    snn_scan<<<1, 1024, 0, stream>>>(w, mu, v0, i0, ic, u_init, u_re,
                                     out, ws_eidx, ws_cnt, ws_snap);

    snn_replay<<<NCHUNK * 8, 256, 0, stream>>>(w, mu, ic, u_re, out,
                                               ws_eidx, ws_cnt, ws_snap);
}

// Round 6
// 3594.471 us; speedup vs baseline: 1.3735x; 1.3735x over previous
//
#include <hip/hip_runtime.h>
#include <cmath>
#include <climits>

#define N_ 2048
#define T_ 4096
#define MAXSP 256
#define CHUNK 256
#define NCHUNK (T_ / CHUNK)   // 16

// ---------------- workspace layout (d_ws) ----------------
#define WS_EIDX_OFF   0
#define WS_CNT_OFF    (T_ * 4)
#define WS_SNAP_OFF   (T_ * 4 + NCHUNK * 4)

typedef float f2 __attribute__((ext_vector_type(2)));

__device__ __forceinline__ int imin(int a, int b) { return a < b ? a : b; }

// ---- packed fp32 ops (VOP3P, gfx950) — bit-identical to scalar f32 ----
__device__ __forceinline__ f2 pk_add(f2 a, f2 b) {
    f2 d; asm("v_pk_add_f32 %0, %1, %2" : "=v"(d) : "v"(a), "v"(b)); return d;
}
__device__ __forceinline__ f2 pk_mul(f2 a, f2 b) {
    f2 d; asm("v_pk_mul_f32 %0, %1, %2" : "=v"(d) : "v"(a), "v"(b)); return d;
}
__device__ __forceinline__ f2 pk_sub(f2 a, f2 b) {   // a - b
    f2 d; asm("v_pk_add_f32 %0, %1, %2 neg_lo:[0,1] neg_hi:[0,1]"
              : "=v"(d) : "v"(a), "v"(b)); return d;
}

// Raw workgroup barrier with LDS visibility only (no vmcnt drain):
// global prefetches (ic, u_re, w-row) stay in flight across it.
__device__ __forceinline__ void lds_barrier() {
    asm volatile("s_waitcnt lgkmcnt(0)\n\ts_barrier" ::: "memory");
}

// Fill tevents/yevents with +inf, event_types with 0; ws_eidx with -1.
__global__ void snn_init_tail(float* __restrict__ out, int* __restrict__ ws_eidx) {
    const size_t base    = (size_t)T_ * N_ * 3;
    const size_t inf_cnt = (size_t)MAXSP + (size_t)MAXSP * N_ * 3;
    const size_t tot     = inf_cnt + (size_t)MAXSP * N_;
    size_t idx = (size_t)blockIdx.x * blockDim.x + threadIdx.x;
    if (idx < tot) {
        out[base + idx] = (idx < inf_cnt) ? __builtin_inff() : 0.0f;
    }
    if (idx < T_) ws_eidx[idx] = -1;   // scan writes only on events
}

// ---------------- Kernel A: sequential scan (1 WG) ----------------------
// EXACT R1 structure (best measured: 2821 us).  Changes are additive only:
//   - packed f32 asm for the f2 arithmetic (half the VALU instrs)
//   - ws_eidx written only on events (pre-init to -1 by init kernel)
//   - LDS slot reset moved to wave 8 (tid 512) to de-load wave 0
//   - prefetch addresses indexed (uniform-scalarizable) instead of
//     per-lane 64-bit pointer bumps
extern "C" __global__ void __launch_bounds__(1024)
snn_scan(const float* __restrict__ w,   const float* __restrict__ mu,
         const float* __restrict__ v0,  const float* __restrict__ i0,
         const float* __restrict__ ic,  const float* __restrict__ u_init,
         const float* __restrict__ u_re, float* __restrict__ out,
         int* __restrict__ ws_eidx, int* __restrict__ ws_cnt,
         float* __restrict__ ws_snap)
{
#pragma clang fp contract(off)
    const int tid = threadIdx.x;
    const int n0  = tid * 2;             // two adjacent neurons -> f2 ops
    const int wv  = tid >> 6, lane = tid & 63;
    const float dt = 1.0f / 4096.0f;     // exact: 2^-12
    const float mu1 = mu[0], mu2 = mu[1];

    // broadcast constants as f2 register pairs for pk ops
    f2 dtv;   dtv.x = dt;    dtv.y = dt;
    f2 mu1v;  mu1v.x = mu1;  mu1v.y = mu1;
    f2 nmu2v; nmu2v.x = -mu2; nmu2v.y = -mu2;
    f2 onev;  onev.x = 1.0f; onev.y = 1.0f;

    float* tev = out + (size_t)T_ * N_ * 3;
    float* nsp = tev + MAXSP + (size_t)MAXSP * N_ * 3 + (size_t)MAXSP * N_;

    // pipeline state: (vc,sc) = post-transition state of step k-1;
    // i1p = pre-w i1 of step k-1; (evp,w2) = pending event / w-row load.
    f2 vc, sc, i1p;
    vc  = *(const f2*)(v0 + n0);
    i1p = *(const f2*)(i0 + n0);
    { f2 a = *(const f2*)(u_init + n0);
      sc.x = logf(a.x) - 0.01f; sc.y = logf(a.y) - 0.01f; }  // one-time precise

    bool evp = false;
    f2 w2; w2.x = 0.0f; w2.y = 0.0f;

    // Slot lifecycle (mod 4): atomics at iter s (pre-barrier) -> read at
    // iter s (post-barrier) -> reset at iter s (right after read, targeting
    // slot s+2, done by wave 8) -> next atomics at iter s+2.
    __shared__ int red[4];
    if (tid == 0) { red[0] = INT_MAX; red[1] = INT_MAX;
                    red[2] = INT_MAX; red[3] = INT_MAX; }

    // 2-deep prefetch pipeline for ic and u_re (indexed addressing:
    // uniform row offset scalarizes; per-lane part is the fixed n0*4)
    f2 icA = *(const f2*)(ic + n0);
    f2 icB = *(const f2*)(ic + N_ + n0);
    f2 uA  = *(const f2*)(u_re + n0);
    f2 uB  = *(const f2*)(u_re + N_ + n0);

    lds_barrier();   // red[] init visible before first atomics

    int cnt = 0;
#pragma unroll 4
    for (int k = 0; k < T_; ++k) {
        // [1] softplus + mask_k from (vc, sc) — independent of pending w-row.
        // Fast path: for v >= 16, fmax(v,0)+__logf(1+__expf(-v)) rounds to
        // EXACTLY v in fp32, so both paths are bit-identical; take the
        // transcendental path only if any lane in the wave has v < 16.
        f2 sp;
        bool slow = (fminf(vc.x, vc.y) < 16.0f);
        if (__ballot(slow)) {
            sp.x = fmaxf(vc.x, 0.0f) + __logf(1.0f + __expf(-fabsf(vc.x)));
            sp.y = fmaxf(vc.y, 0.0f) + __logf(1.0f + __expf(-fabsf(vc.y)));
        } else {
            sp = vc;
        }
        f2 s1 = pk_add(sc, pk_mul(dtv, sp));
        bool m0 = (s1.x >= 0.0f), m1 = (s1.y >= 0.0f);

        // wave candidate, fully scalar: min spiking neuron in this wave is
        // wavebase + min(2*ctz(b0), 2*ctz(b1)+1).  One atomicMin per wave.
        unsigned long long b0 = __ballot(m0);
        unsigned long long b1 = __ballot(m1);
        if (b0 | b1) {
            int c0 = b0 ? (((int)__ffsll((long long)b0) - 1) << 1)       : INT_MAX;
            int c1 = b1 ? ((((int)__ffsll((long long)b1) - 1) << 1) | 1) : INT_MAX;
            int cand = (wv << 7) + imin(c0, c1);
            if (lane == 0) atomicMin(&red[k & 3], cand);
        }

        // [2] barrier (drains this slot's atomics) + broadcast read
        lds_barrier();
        int eidx = red[k & 3];
        eidx = __builtin_amdgcn_readfirstlane(eidx);   // scalarize
        if (tid == 512) red[(k + 2) & 3] = INT_MAX;    // deferred reset (wave 8)

        // [3] finalize i_{k-1}: waits the pending w[k-1] row load
        f2 ip = i1p;
        if (evp) ip = pk_add(ip, w2);

        // chunk snapshot: state after step k-1 (= chunk-start state)
        if ((k & (CHUNK - 1)) == 0) {
            const int c = k >> 8;
            float* spn = ws_snap + (size_t)c * 3 * N_;
            *(f2*)(spn + n0)          = vc;
            *(f2*)(spn + N_ + n0)     = ip;
            *(f2*)(spn + 2 * N_ + n0) = sc;
            if (tid == 0) ws_cnt[c] = cnt;
        }

        // [4] Euler for step k — reference op order preserved exactly:
        // v1 = vc + dt*(mu1*((ip + icA) - vc)); i1p = ip + dt*((-mu2)*ip)
        f2 v1 = pk_add(vc, pk_mul(dtv, pk_mul(mu1v, pk_sub(pk_add(ip, icA), vc))));
        i1p   = pk_add(ip, pk_mul(dtv, pk_mul(nmu2v, ip)));

        // [5]+[6] event handling + per-lane transitions
        evp = (eidx != INT_MAX);
        f2 v1m = pk_sub(v1, onev);             // v1 - 1.0 (packed)
        vc.x = m0 ? v1m.x : v1.x;
        vc.y = m1 ? v1m.y : v1.y;
        if (evp) {
            // issue next pending w-row load (waited next iteration at [3])
            w2 = *(const f2*)(w + (size_t)eidx * N_ + n0);
            sc.x = m0 ? (__logf(uA.x) - 0.01f) : s1.x;
            sc.y = m1 ? (__logf(uA.y) - 0.01f) : s1.y;
            if (tid == 0) {
                ws_eidx[k] = eidx;             // only on events (pre-init -1)
                if (cnt < MAXSP) tev[cnt] = (float)(k + 1) * dt;
            }
            if (cnt < MAXSP) cnt++;
        } else {
            sc = s1;
        }

        // [7] advance 2-deep prefetch (indexed, scalarizable addressing)
        icA = icB; uA = uB;
        if (k + 2 < T_) {
            icB = *(const f2*)(ic   + (size_t)(k + 2) * N_ + n0);
            uB  = *(const f2*)(u_re + (size_t)(k + 2) * N_ + n0);
        }
    }

    if (tid == 0) nsp[0] = (float)cnt;
}

// ---------------- Kernel B: parallel replay ----------------
extern "C" __global__ void __launch_bounds__(256)
snn_replay(const float* __restrict__ w,   const float* __restrict__ mu,
           const float* __restrict__ ic,  const float* __restrict__ u_re,
           float* __restrict__ out,
           const int* __restrict__ ws_eidx, const int* __restrict__ ws_cnt,
           const float* __restrict__ ws_snap)
{
#pragma clang fp contract(off)
    const int c = blockIdx.x >> 3;                       // chunk
    const int n = ((blockIdx.x & 7) << 8) + threadIdx.x; // neuron
    const float dt = 1.0f / 4096.0f;
    const float mu1 = mu[0], mu2 = mu[1];

    float* ys  = out;
    float* yev = out + (size_t)T_ * N_ * 3 + MAXSP;
    float* et  = yev + (size_t)MAXSP * N_ * 3;

    const float* sp = ws_snap + (size_t)c * 3 * N_;
    float v  = sp[n];
    float ii = sp[N_ + n];
    float ss = sp[2 * N_ + n];
    int cnt = ws_cnt[c];

    const int t0 = c << 8;
    const float* icp = ic + (size_t)t0 * N_ + n;
    const float* up  = u_re + (size_t)t0 * N_ + n;
    float* yr = ys + ((size_t)t0 * N_ + n) * 3;

    for (int k = 0; k < CHUNK; ++k) {
        const int t = t0 + k;
        const int e = ws_eidx[t];          // uniform scalar load
        const float icv = icp[0];

        float v1 = v + dt * (mu1 * ((ii + icv) - v));
        float i1 = ii + dt * ((-mu2) * ii);
        // same bit-exact fast/slow softplus as the scan
        float spv;
        if (__ballot(v < 16.0f)) {
            spv = fmaxf(v, 0.0f) + __logf(1.0f + __expf(-fabsf(v)));
        } else {
            spv = v;
        }
        float s1 = ss + dt * spv;
        bool m = (s1 >= 0.0f);

        if (e >= 0) {                      // event step (uniform branch)
            float wv_ = w[(size_t)e * N_ + n];
            float uu  = up[0];
            if (cnt < MAXSP) {             // record pre-transition state
                float* ye = yev + ((size_t)cnt * N_ + n) * 3;
                ye[0] = v1; ye[1] = i1; ye[2] = s1;
                et[(size_t)cnt * N_ + n] = m ? 1.0f : 0.0f;
                cnt++;
            }
            v  = m ? (v1 - 1.0f) : v1;
            ii = i1 + wv_;
            ss = m ? (__logf(uu) - 0.01f) : s1;
        } else {
            v = v1; ii = i1; ss = s1;
        }

        yr[0] = v; yr[1] = ii; yr[2] = ss;

        icp += N_; up += N_; yr += (size_t)3 * N_;
    }
}

extern "C" void kernel_launch(void* const* d_in, const int* in_sizes, int n_in,
                              void* d_out, int out_size, void* d_ws, size_t ws_size,
                              hipStream_t stream) {
    const float* w      = (const float*)d_in[0];
    const float* mu     = (const float*)d_in[1];
    const float* v0     = (const float*)d_in[2];
    const float* i0     = (const float*)d_in[3];
    const float* ic     = (const float*)d_in[4];
    const float* u_init = (const float*)d_in[5];
    const float* u_re   = (const float*)d_in[6];
    float* out = (float*)d_out;

    char* ws = (char*)d_ws;
    int*   ws_eidx = (int*)(ws + WS_EIDX_OFF);
    int*   ws_cnt  = (int*)(ws + WS_CNT_OFF);
    float* ws_snap = (float*)(ws + WS_SNAP_OFF);

    const size_t tail = (size_t)MAXSP + (size_t)MAXSP * N_ * 3 + (size_t)MAXSP * N_;
    int blocks = (int)((tail + 255) / 256);
    snn_init_tail<<<blocks, 256, 0, stream>>>(out, ws_eidx);

    snn_scan<<<1, 1024, 0, stream>>>(w, mu, v0, i0, ic, u_init, u_re,
                                     out, ws_eidx, ws_cnt, ws_snap);

    snn_replay<<<NCHUNK * 8, 256, 0, stream>>>(w, mu, ic, u_re, out,
                                               ws_eidx, ws_cnt, ws_snap);
}

// Round 7
// 3015.032 us; speedup vs baseline: 1.6374x; 1.1922x over previous
//
#include <hip/hip_runtime.h>
#include <cmath>
#include <climits>

#define N_ 2048
#define T_ 4096
#define MAXSP 256
#define CHUNK 64
#define NCHUNK (T_ / CHUNK)   // 64

// ---------------- workspace layout (d_ws) ----------------
// Snapshots now live in the output buffer itself (ys[t] IS the state after
// step t), so ws holds only the event index stream and per-chunk counts.
#define WS_EIDX_OFF   0
#define WS_CNT_OFF    (T_ * 4)

typedef float f2 __attribute__((ext_vector_type(2)));

__device__ __forceinline__ int imin(int a, int b) { return a < b ? a : b; }

// Raw workgroup barrier with LDS visibility only (no vmcnt drain):
// global prefetches (ic, u_re, w-row) stay in flight across it.
__device__ __forceinline__ void lds_barrier() {
    asm volatile("s_waitcnt lgkmcnt(0)\n\ts_barrier" ::: "memory");
}

// Fill tevents/yevents with +inf, event_types with 0.
__global__ void snn_init_tail(float* __restrict__ out) {
    const size_t base    = (size_t)T_ * N_ * 3;
    const size_t inf_cnt = (size_t)MAXSP + (size_t)MAXSP * N_ * 3;
    const size_t tot     = inf_cnt + (size_t)MAXSP * N_;
    size_t idx = (size_t)blockIdx.x * blockDim.x + threadIdx.x;
    if (idx < tot) {
        out[base + idx] = (idx < inf_cnt) ? __builtin_inff() : 0.0f;
    }
}

// ---------------- Kernel A: sequential scan (1 WG) ----------------------
// VERBATIM R1 structure (best measured: 2821 us scan).  The ONLY edits:
//   - snapshot block: every 64 steps, write the chunk-start state into
//     ys[k-1] (it IS that state) instead of a separate ws_snap buffer.
//     Replay blocks of the previous chunk later rewrite the same row with
//     bit-identical values (same formulas from the same snapshot) ->
//     benign same-bits race.  Chunk 0 needs no snapshot (replay derives
//     it from v0/i0/u_init with the same precise logf).
//   - removed one dead duplicate __ballot.
extern "C" __global__ void __launch_bounds__(1024)
snn_scan(const float* __restrict__ w,   const float* __restrict__ mu,
         const float* __restrict__ v0,  const float* __restrict__ i0,
         const float* __restrict__ ic,  const float* __restrict__ u_init,
         const float* __restrict__ u_re, float* __restrict__ out,
         int* __restrict__ ws_eidx, int* __restrict__ ws_cnt)
{
#pragma clang fp contract(off)
    const int tid = threadIdx.x;
    const int n0  = tid * 2;             // two adjacent neurons -> f2 ops
    const int wv  = tid >> 6, lane = tid & 63;
    const float dt = 1.0f / 4096.0f;     // exact: 2^-12
    const float mu1 = mu[0], mu2 = mu[1];

    float* tev = out + (size_t)T_ * N_ * 3;
    float* nsp = tev + MAXSP + (size_t)MAXSP * N_ * 3 + (size_t)MAXSP * N_;

    // pipeline state: (vc,sc) = post-transition state of step k-1;
    // i1p = pre-w i1 of step k-1; (evp,w2) = pending event / w-row load.
    f2 vc, sc, i1p;
    vc  = *(const f2*)(v0 + n0);
    i1p = *(const f2*)(i0 + n0);
    { f2 a = *(const f2*)(u_init + n0);
      sc.x = logf(a.x) - 0.01f; sc.y = logf(a.y) - 0.01f; }  // one-time precise

    bool evp = false;
    f2 w2; w2.x = 0.0f; w2.y = 0.0f;

    // Slot lifecycle (mod 4): atomics at iter s (pre-barrier) -> read at
    // iter s (post-barrier) -> reset by tid0 at iter s (right after read,
    // targeting slot s+2) -> next atomics at iter s+2 (>=1 barrier apart).
    __shared__ int red[4];
    if (tid == 0) { red[0] = INT_MAX; red[1] = INT_MAX;
                    red[2] = INT_MAX; red[3] = INT_MAX; }

    // 2-deep prefetch pipeline for ic and u_re
    const float* icp = ic + n0;
    const float* up  = u_re + n0;
    f2 icA = *(const f2*)(icp);
    f2 icB = *(const f2*)(icp + N_);
    f2 uA  = *(const f2*)(up);
    f2 uB  = *(const f2*)(up + N_);
    icp += 2 * N_; up += 2 * N_;

    lds_barrier();   // red[] init visible before first atomics

    int cnt = 0;
#pragma unroll 4
    for (int k = 0; k < T_; ++k) {
        // [1] softplus + mask_k from (vc, sc) — independent of pending w-row.
        // Fast path: for v >= 16, fmax(v,0)+__logf(1+__expf(-v)) rounds to
        // EXACTLY v in fp32, so both paths are bit-identical; take the
        // transcendental path only if any lane in the wave has v < 16.
        f2 sp;
        bool slow = (fminf(vc.x, vc.y) < 16.0f);
        if (__ballot(slow)) {
            sp.x = fmaxf(vc.x, 0.0f) + __logf(1.0f + __expf(-fabsf(vc.x)));
            sp.y = fmaxf(vc.y, 0.0f) + __logf(1.0f + __expf(-fabsf(vc.y)));
        } else {
            sp = vc;
        }
        f2 s1 = sc + dt * sp;
        bool m0 = (s1.x >= 0.0f), m1 = (s1.y >= 0.0f);

        // wave candidate, fully scalar: min spiking neuron in this wave is
        // wavebase + min(2*ctz(b0), 2*ctz(b1)+1).  One atomicMin per wave.
        unsigned long long b0 = __ballot(m0);
        unsigned long long b1 = __ballot(m1);
        if (b0 | b1) {
            int c0 = b0 ? (((int)__ffsll((long long)b0) - 1) << 1)       : INT_MAX;
            int c1 = b1 ? ((((int)__ffsll((long long)b1) - 1) << 1) | 1) : INT_MAX;
            int cand = (wv << 7) + imin(c0, c1);
            if (lane == 0) atomicMin(&red[k & 3], cand);
        }

        // [2] barrier (drains this slot's atomics) + broadcast read
        lds_barrier();
        int eidx = red[k & 3];
        eidx = __builtin_amdgcn_readfirstlane(eidx);   // scalarize
        if (tid == 0) red[(k + 2) & 3] = INT_MAX;      // deferred reset

        // [3] finalize i_{k-1}: waits the pending w[k-1] row load
        f2 ip = i1p;
        if (evp) ip += w2;

        // chunk snapshot: (vc, ip, sc) = state after step k-1 = ys[k-1].
        // Write it straight into the output (interleaved layout); replay
        // rewrites the same row with bit-identical values later.
        if ((k & (CHUNK - 1)) == 0) {
            if (k) {
                float* yrow = out + ((size_t)(k - 1) * N_ + n0) * 3;
                yrow[0] = vc.x; yrow[1] = ip.x; yrow[2] = sc.x;
                yrow[3] = vc.y; yrow[4] = ip.y; yrow[5] = sc.y;
            }
            if (tid == 0) ws_cnt[k >> 6] = cnt;
        }

        // [4] Euler for step k — reference op order, no FMA contraction
        f2 v1 = vc + dt * (mu1 * ((ip + icA) - vc));
        i1p   = ip + dt * ((-mu2) * ip);

        // [5]+[6] event handling + per-lane transitions
        evp = (eidx != INT_MAX);
        vc.x = m0 ? (v1.x - 1.0f) : v1.x;
        vc.y = m1 ? (v1.y - 1.0f) : v1.y;
        if (evp) {
            // issue next pending w-row load (waited next iteration at [3])
            w2 = *(const f2*)(w + (size_t)eidx * N_ + n0);
            sc.x = m0 ? (__logf(uA.x) - 0.01f) : s1.x;
            sc.y = m1 ? (__logf(uA.y) - 0.01f) : s1.y;
            if (tid == 0) {
                ws_eidx[k] = eidx;
                if (cnt < MAXSP) tev[cnt] = (float)(k + 1) * dt;
            }
            if (cnt < MAXSP) cnt++;
        } else {
            sc = s1;
            if (tid == 0) ws_eidx[k] = -1;
        }

        // [7] advance 2-deep prefetch
        icA = icB; uA = uB;
        if (k + 2 < T_) {
            icB = *(const f2*)icp;
            uB  = *(const f2*)up;
            icp += N_; up += N_;
        }
    }

    if (tid == 0) nsp[0] = (float)cnt;
}

// ---------------- Kernel B: parallel replay (64 chunks x 8 blocks) -------
extern "C" __global__ void __launch_bounds__(256)
snn_replay(const float* __restrict__ w,   const float* __restrict__ mu,
           const float* __restrict__ v0,  const float* __restrict__ i0,
           const float* __restrict__ ic,  const float* __restrict__ u_re,
           const float* __restrict__ u_init, float* __restrict__ out,
           const int* __restrict__ ws_eidx, const int* __restrict__ ws_cnt)
{
#pragma clang fp contract(off)
    const int c = blockIdx.x >> 3;                       // chunk
    const int n = ((blockIdx.x & 7) << 8) + threadIdx.x; // neuron
    const float dt = 1.0f / 4096.0f;
    const float mu1 = mu[0], mu2 = mu[1];

    float* ys  = out;
    float* yev = out + (size_t)T_ * N_ * 3 + MAXSP;
    float* et  = yev + (size_t)MAXSP * N_ * 3;

    float v, ii, ss;
    if (c == 0) {
        // derive chunk-0 start state exactly as the scan did (precise logf)
        v  = v0[n];
        ii = i0[n];
        ss = logf(u_init[n]) - 0.01f;
    } else {
        // ys[c*CHUNK - 1] IS the chunk-start state (written by the scan;
        // later rewritten bit-identically by the previous chunk's replay)
        const float* sp = ys + ((size_t)(c * CHUNK - 1) * N_ + n) * 3;
        v  = sp[0];
        ii = sp[1];
        ss = sp[2];
    }
    int cnt = ws_cnt[c];

    const int t0 = c * CHUNK;
    const float* icp = ic + (size_t)t0 * N_ + n;
    const float* up  = u_re + (size_t)t0 * N_ + n;
    float* yr = ys + ((size_t)t0 * N_ + n) * 3;

    for (int k = 0; k < CHUNK; ++k) {
        const int t = t0 + k;
        const int e = ws_eidx[t];          // uniform scalar load
        const float icv = icp[0];

        float v1 = v + dt * (mu1 * ((ii + icv) - v));
        float i1 = ii + dt * ((-mu2) * ii);
        // same bit-exact fast/slow softplus as the scan
        float spv;
        if (__ballot(v < 16.0f)) {
            spv = fmaxf(v, 0.0f) + __logf(1.0f + __expf(-fabsf(v)));
        } else {
            spv = v;
        }
        float s1 = ss + dt * spv;
        bool m = (s1 >= 0.0f);

        if (e >= 0) {                      // event step (uniform branch)
            float wv_ = w[(size_t)e * N_ + n];
            float uu  = up[0];
            if (cnt < MAXSP) {             // record pre-transition state
                float* ye = yev + ((size_t)cnt * N_ + n) * 3;
                ye[0] = v1; ye[1] = i1; ye[2] = s1;
                et[(size_t)cnt * N_ + n] = m ? 1.0f : 0.0f;
                cnt++;
            }
            v  = m ? (v1 - 1.0f) : v1;
            ii = i1 + wv_;
            ss = m ? (__logf(uu) - 0.01f) : s1;
        } else {
            v = v1; ii = i1; ss = s1;
        }

        yr[0] = v; yr[1] = ii; yr[2] = ss;

        icp += N_; up += N_; yr += (size_t)3 * N_;
    }
}

extern "C" void kernel_launch(void* const* d_in, const int* in_sizes, int n_in,
                              void* d_out, int out_size, void* d_ws, size_t ws_size,
                              hipStream_t stream) {
    const float* w      = (const float*)d_in[0];
    const float* mu     = (const float*)d_in[1];
    const float* v0     = (const float*)d_in[2];
    const float* i0     = (const float*)d_in[3];
    const float* ic     = (const float*)d_in[4];
    const float* u_init = (const float*)d_in[5];
    const float* u_re   = (const float*)d_in[6];
    float* out = (float*)d_out;

    char* ws = (char*)d_ws;
    int*   ws_eidx = (int*)(ws + WS_EIDX_OFF);
    int*   ws_cnt  = (int*)(ws + WS_CNT_OFF);

    const size_t tail = (size_t)MAXSP + (size_t)MAXSP * N_ * 3 + (size_t)MAXSP * N_;
    int blocks = (int)((tail + 255) / 256);
    snn_init_tail<<<blocks, 256, 0, stream>>>(out);

    snn_scan<<<1, 1024, 0, stream>>>(w, mu, v0, i0, ic, u_init, u_re,
                                     out, ws_eidx, ws_cnt);

    snn_replay<<<NCHUNK * 8, 256, 0, stream>>>(w, mu, v0, i0, ic, u_re,
                                               u_init, out, ws_eidx, ws_cnt);
}

// Round 8
// 3005.420 us; speedup vs baseline: 1.6427x; 1.0032x over previous
//
#include <hip/hip_runtime.h>
#include <cmath>
#include <climits>

#define N_ 2048
#define T_ 4096
#define MAXSP 256
#define CHUNK 32
#define NCHUNK (T_ / CHUNK)       // 128
#define REPLAY_BLOCKS (NCHUNK * 8)  // 1024
#define FILL_BLOCKS 256
#define TOTAL_BLOCKS (REPLAY_BLOCKS + FILL_BLOCKS)

// ---------------- workspace layout (d_ws) ----------------
// Snapshots live in the output buffer itself (ys[t] IS the state after
// step t), so ws holds only the event index stream and per-chunk counts.
#define WS_EIDX_OFF   0
#define WS_CNT_OFF    (T_ * 4)

typedef float f2 __attribute__((ext_vector_type(2)));

__device__ __forceinline__ int imin(int a, int b) { return a < b ? a : b; }

// Raw workgroup barrier with LDS visibility only (no vmcnt drain):
// global prefetches (ic, u_re, w-row) stay in flight across it.
__device__ __forceinline__ void lds_barrier() {
    asm volatile("s_waitcnt lgkmcnt(0)\n\ts_barrier" ::: "memory");
}

// ---------------- Kernel A: sequential scan (1 WG) ----------------------
// VERBATIM R7 scan (measured 2838 us) with only the CHUNK constants
// changed (snapshot every 32 steps, ws_cnt[k>>5]).  Do NOT reorder this
// loop: 5/5 structural modifications regressed (R2,R3,R4,R5,R6).
extern "C" __global__ void __launch_bounds__(1024)
snn_scan(const float* __restrict__ w,   const float* __restrict__ mu,
         const float* __restrict__ v0,  const float* __restrict__ i0,
         const float* __restrict__ ic,  const float* __restrict__ u_init,
         const float* __restrict__ u_re, float* __restrict__ out,
         int* __restrict__ ws_eidx, int* __restrict__ ws_cnt)
{
#pragma clang fp contract(off)
    const int tid = threadIdx.x;
    const int n0  = tid * 2;             // two adjacent neurons -> f2 ops
    const int wv  = tid >> 6, lane = tid & 63;
    const float dt = 1.0f / 4096.0f;     // exact: 2^-12
    const float mu1 = mu[0], mu2 = mu[1];

    float* tev = out + (size_t)T_ * N_ * 3;
    float* nsp = tev + MAXSP + (size_t)MAXSP * N_ * 3 + (size_t)MAXSP * N_;

    // pipeline state: (vc,sc) = post-transition state of step k-1;
    // i1p = pre-w i1 of step k-1; (evp,w2) = pending event / w-row load.
    f2 vc, sc, i1p;
    vc  = *(const f2*)(v0 + n0);
    i1p = *(const f2*)(i0 + n0);
    { f2 a = *(const f2*)(u_init + n0);
      sc.x = logf(a.x) - 0.01f; sc.y = logf(a.y) - 0.01f; }  // one-time precise

    bool evp = false;
    f2 w2; w2.x = 0.0f; w2.y = 0.0f;

    // Slot lifecycle (mod 4): atomics at iter s (pre-barrier) -> read at
    // iter s (post-barrier) -> reset by tid0 at iter s (right after read,
    // targeting slot s+2) -> next atomics at iter s+2 (>=1 barrier apart).
    __shared__ int red[4];
    if (tid == 0) { red[0] = INT_MAX; red[1] = INT_MAX;
                    red[2] = INT_MAX; red[3] = INT_MAX; }

    // 2-deep prefetch pipeline for ic and u_re
    const float* icp = ic + n0;
    const float* up  = u_re + n0;
    f2 icA = *(const f2*)(icp);
    f2 icB = *(const f2*)(icp + N_);
    f2 uA  = *(const f2*)(up);
    f2 uB  = *(const f2*)(up + N_);
    icp += 2 * N_; up += 2 * N_;

    lds_barrier();   // red[] init visible before first atomics

    int cnt = 0;
#pragma unroll 4
    for (int k = 0; k < T_; ++k) {
        // [1] softplus + mask_k from (vc, sc) — independent of pending w-row.
        // Fast path: for v >= 16, fmax(v,0)+__logf(1+__expf(-v)) rounds to
        // EXACTLY v in fp32, so both paths are bit-identical; take the
        // transcendental path only if any lane in the wave has v < 16.
        f2 sp;
        bool slow = (fminf(vc.x, vc.y) < 16.0f);
        if (__ballot(slow)) {
            sp.x = fmaxf(vc.x, 0.0f) + __logf(1.0f + __expf(-fabsf(vc.x)));
            sp.y = fmaxf(vc.y, 0.0f) + __logf(1.0f + __expf(-fabsf(vc.y)));
        } else {
            sp = vc;
        }
        f2 s1 = sc + dt * sp;
        bool m0 = (s1.x >= 0.0f), m1 = (s1.y >= 0.0f);

        // wave candidate, fully scalar: min spiking neuron in this wave is
        // wavebase + min(2*ctz(b0), 2*ctz(b1)+1).  One atomicMin per wave.
        unsigned long long b0 = __ballot(m0);
        unsigned long long b1 = __ballot(m1);
        if (b0 | b1) {
            int c0 = b0 ? (((int)__ffsll((long long)b0) - 1) << 1)       : INT_MAX;
            int c1 = b1 ? ((((int)__ffsll((long long)b1) - 1) << 1) | 1) : INT_MAX;
            int cand = (wv << 7) + imin(c0, c1);
            if (lane == 0) atomicMin(&red[k & 3], cand);
        }

        // [2] barrier (drains this slot's atomics) + broadcast read
        lds_barrier();
        int eidx = red[k & 3];
        eidx = __builtin_amdgcn_readfirstlane(eidx);   // scalarize
        if (tid == 0) red[(k + 2) & 3] = INT_MAX;      // deferred reset

        // [3] finalize i_{k-1}: waits the pending w[k-1] row load
        f2 ip = i1p;
        if (evp) ip += w2;

        // chunk snapshot: (vc, ip, sc) = state after step k-1 = ys[k-1].
        // Write it straight into the output (interleaved layout); replay
        // rewrites the same row with bit-identical values later.
        if ((k & (CHUNK - 1)) == 0) {
            if (k) {
                float* yrow = out + ((size_t)(k - 1) * N_ + n0) * 3;
                yrow[0] = vc.x; yrow[1] = ip.x; yrow[2] = sc.x;
                yrow[3] = vc.y; yrow[4] = ip.y; yrow[5] = sc.y;
            }
            if (tid == 0) ws_cnt[k >> 5] = cnt;
        }

        // [4] Euler for step k — reference op order, no FMA contraction
        f2 v1 = vc + dt * (mu1 * ((ip + icA) - vc));
        i1p   = ip + dt * ((-mu2) * ip);

        // [5]+[6] event handling + per-lane transitions
        evp = (eidx != INT_MAX);
        vc.x = m0 ? (v1.x - 1.0f) : v1.x;
        vc.y = m1 ? (v1.y - 1.0f) : v1.y;
        if (evp) {
            // issue next pending w-row load (waited next iteration at [3])
            w2 = *(const f2*)(w + (size_t)eidx * N_ + n0);
            sc.x = m0 ? (__logf(uA.x) - 0.01f) : s1.x;
            sc.y = m1 ? (__logf(uA.y) - 0.01f) : s1.y;
            if (tid == 0) {
                ws_eidx[k] = eidx;
                if (cnt < MAXSP) tev[cnt] = (float)(k + 1) * dt;
            }
            if (cnt < MAXSP) cnt++;
        } else {
            sc = s1;
            if (tid == 0) ws_eidx[k] = -1;
        }

        // [7] advance 2-deep prefetch
        icA = icB; uA = uB;
        if (k + 2 < T_) {
            icB = *(const f2*)icp;
            uB  = *(const f2*)up;
            icp += N_; up += N_;
        }
    }

    if (tid == 0) nsp[0] = (float)cnt;
}

// ---------------- Kernel B: replay (1024 blocks) + tail-fill (256) -------
// Runs after the scan, so nsp[0] (= total event count ns) is available:
// fill blocks initialize only event-slots [ns, MAXSP) of tev/yev/et —
// disjoint from the rows [0, ns) that replay blocks write.
extern "C" __global__ void __launch_bounds__(256)
snn_replay(const float* __restrict__ w,   const float* __restrict__ mu,
           const float* __restrict__ v0,  const float* __restrict__ i0,
           const float* __restrict__ ic,  const float* __restrict__ u_re,
           const float* __restrict__ u_init, float* __restrict__ out,
           const int* __restrict__ ws_eidx, const int* __restrict__ ws_cnt)
{
#pragma clang fp contract(off)
    float* ys  = out;
    float* tev = out + (size_t)T_ * N_ * 3;
    float* yev = tev + MAXSP;
    float* et  = yev + (size_t)MAXSP * N_ * 3;
    float* nsp = et + (size_t)MAXSP * N_;

    if (blockIdx.x >= REPLAY_BLOCKS) {
        // ---- tail-fill role: slots [ns, MAXSP) get inf/inf/0 ------------
        const int ns = imin((int)nsp[0], MAXSP);
        const int rem = MAXSP - ns;
        if (rem <= 0) return;
        const int fb = blockIdx.x - REPLAY_BLOCKS;
        // tev tail
        for (int j = fb * 256 + threadIdx.x; j < rem; j += FILL_BLOCKS * 256)
            tev[ns + j] = __builtin_inff();
        // yev + et tails: 8192 elems per slot (6144 yev + 2048 et)
        const size_t tot = (size_t)rem * 8192;
        for (size_t idx = (size_t)fb * 256 + threadIdx.x; idx < tot;
             idx += (size_t)FILL_BLOCKS * 256) {
            const int j = ns + (int)(idx >> 13);
            const int r = (int)(idx & 8191);
            if (r < 6144) yev[(size_t)j * 6144 + r] = __builtin_inff();
            else          et[(size_t)j * 2048 + (r - 6144)] = 0.0f;
        }
        return;
    }

    // ---- replay role: chunk c, neuron slice ----
    const int c = blockIdx.x >> 3;                       // chunk
    const int n = ((blockIdx.x & 7) << 8) + threadIdx.x; // neuron
    const float dt = 1.0f / 4096.0f;
    const float mu1 = mu[0], mu2 = mu[1];

    float v, ii, ss;
    if (c == 0) {
        // derive chunk-0 start state exactly as the scan did (precise logf)
        v  = v0[n];
        ii = i0[n];
        ss = logf(u_init[n]) - 0.01f;
    } else {
        // ys[c*CHUNK - 1] IS the chunk-start state (written by the scan;
        // later rewritten bit-identically by the previous chunk's replay)
        const float* sp = ys + ((size_t)(c * CHUNK - 1) * N_ + n) * 3;
        v  = sp[0];
        ii = sp[1];
        ss = sp[2];
    }
    int cnt = ws_cnt[c];

    const int t0 = c * CHUNK;
    const float* icp = ic + (size_t)t0 * N_ + n;
    const float* up  = u_re + (size_t)t0 * N_ + n;
    float* yr = ys + ((size_t)t0 * N_ + n) * 3;

    float icv = icp[0];                    // 1-deep ic prefetch
    for (int k = 0; k < CHUNK; ++k) {
        const int t = t0 + k;
        const int e = ws_eidx[t];          // uniform scalar load
        float icn = 0.0f;
        if (k + 1 < CHUNK) icn = icp[N_];  // issue next row early

        float v1 = v + dt * (mu1 * ((ii + icv) - v));
        float i1 = ii + dt * ((-mu2) * ii);
        // same bit-exact fast/slow softplus as the scan
        float spv;
        if (__ballot(v < 16.0f)) {
            spv = fmaxf(v, 0.0f) + __logf(1.0f + __expf(-fabsf(v)));
        } else {
            spv = v;
        }
        float s1 = ss + dt * spv;
        bool m = (s1 >= 0.0f);

        if (e >= 0) {                      // event step (uniform branch)
            float wv_ = w[(size_t)e * N_ + n];
            float uu  = up[0];
            if (cnt < MAXSP) {             // record pre-transition state
                float* ye = yev + ((size_t)cnt * N_ + n) * 3;
                ye[0] = v1; ye[1] = i1; ye[2] = s1;
                et[(size_t)cnt * N_ + n] = m ? 1.0f : 0.0f;
                cnt++;
            }
            v  = m ? (v1 - 1.0f) : v1;
            ii = i1 + wv_;
            ss = m ? (__logf(uu) - 0.01f) : s1;
        } else {
            v = v1; ii = i1; ss = s1;
        }

        yr[0] = v; yr[1] = ii; yr[2] = ss;

        icv = icn;
        icp += N_; up += N_; yr += (size_t)3 * N_;
    }
}

extern "C" void kernel_launch(void* const* d_in, const int* in_sizes, int n_in,
                              void* d_out, int out_size, void* d_ws, size_t ws_size,
                              hipStream_t stream) {
    const float* w      = (const float*)d_in[0];
    const float* mu     = (const float*)d_in[1];
    const float* v0     = (const float*)d_in[2];
    const float* i0     = (const float*)d_in[3];
    const float* ic     = (const float*)d_in[4];
    const float* u_init = (const float*)d_in[5];
    const float* u_re   = (const float*)d_in[6];
    float* out = (float*)d_out;

    char* ws = (char*)d_ws;
    int*   ws_eidx = (int*)(ws + WS_EIDX_OFF);
    int*   ws_cnt  = (int*)(ws + WS_CNT_OFF);

    snn_scan<<<1, 1024, 0, stream>>>(w, mu, v0, i0, ic, u_init, u_re,
                                     out, ws_eidx, ws_cnt);

    snn_replay<<<TOTAL_BLOCKS, 256, 0, stream>>>(w, mu, v0, i0, ic, u_re,
                                                 u_init, out, ws_eidx, ws_cnt);
}